// Round 10
// baseline (285.268 us; speedup 1.0000x reference)
//
#include <hip/hip_runtime.h>
#include <hip/hip_fp16.h>

// out[n,c,h,w] = sum_{5x5 in-bounds taps} exp(-0.5*||xyz_nbr - xyz_ctr||^2)
//                * mask_nbr * softmax[n,c,nbr]
// OOB taps have weight forced to 0, so staged/loaded slots at clamped
// addresses may hold garbage; they are always multiplied by 0.0f.
//
// R14: persistent strip + 1-tile-deep pipeline. R13 (98us) proved the
// remaining 4x gap between VALU issue (~25us) and duration is per-block
// serial chains: load -> vmcnt -> ds_write -> barrier -> compute, never
// overlapped (occupancy 2x'd THREE times with no effect). R14 makes each
// block own 8 consecutive 4-row tiles (grid 512 = 2 blocks/CU) and
// pipelines: per iteration, ISSUE tile t+1 sm-halo loads into 12 f4 regs,
// compute WEIGHTS for t+1 (xyz L2-hot) into w_h[nxt], COMPUTE tile t from
// sm_s[cur]/w_h[cur] (R13's verified all-b64 fp16 phase 2), then
// WRITE-LATE the staged regs to sm_s[nxt] (vmcnt hidden under compute),
// ONE barrier per tile. Cross-iteration hazards are guarded by that
// barrier; within-iteration ds reorderings touch opposite ping-pong
// buffers -> harmless. LDS 71.7KB -> 2 blocks/CU (residency is proven
// NOT the lever; loads-in-flight-ahead-of-use is).
// Plain __launch_bounds__ (R6/R7: min-waves caps spill catastrophically).
// 1D grid ONLY (2D gridDim.y broke harness graph replay in R3).

#define H_DIM 64
#define W_DIM 2048
#define C_DIM 20
#define N_DIM 8
#define HW (H_DIM * W_DIM)
#define BLOCK 256
#define HT 4               // output h-rows per tile
#define PX 64              // output pixels per block strip
#define RS 8               // staged rows = HT + 4
#define CS 72              // staged cols = PX + 8
#define NGX 18             // float4 groups per staged row
#define NJOB (C_DIM * RS * NGX)   // 2880 stage jobs per tile
#define NIT 12             // ceil(2880/256)
#define NT 8               // tiles per block

struct h4v { __half2 lo, hi; };   // 8B, one b64

__global__ __launch_bounds__(BLOCK) void lcx_kernel(
    const float* __restrict__ xyz,
    const float* __restrict__ sm,
    const int*  __restrict__ mask,
    float* __restrict__ out)
{
    __shared__ __half sm_s[2][C_DIM][RS][CS];  // 46.08 KB
    __shared__ __half w_h[2][HT][25][PX];      // 25.6 KB

    const int b  = blockIdx.x;                 // 512 = 32 pc x 2 hg x 8 n
    const int pc = b & 31;
    const int hg = (b >> 5) & 1;
    const int n  = b >> 6;
    const int w0 = pc << 6;
    const int h0base = hg << 5;
    const int t  = threadIdx.x;

    const float* xyzn  = xyz  + n * 3 * HW;
    const int*   maskn = mask + n * HW;
    const float* smn   = sm   + n * C_DIM * HW;
    float*       outn  = out  + n * C_DIM * HW;

    float4 stg[NIT];

    // ---- stage-issue: tile halo (rows h0s-2..h0s+5) -> 12 f4 regs ----
    auto stage_issue = [&](int h0s) {
        #pragma unroll
        for (int it = 0; it < NIT; ++it) {
            const int j = t + (it << 8);
            if (j < NJOB) {                    // wave-uniform (it=11: wave 0)
                const int grp = j % NGX;
                const int rem = j / NGX;       // c*8 + row
                const int row = rem & 7;
                const int c   = rem >> 3;
                const int hi  = h0s - 2 + row;
                const int hic = (hi < 0) ? 0 : (hi > H_DIM - 1 ? H_DIM - 1 : hi);
                int gc = w0 - 4 + (grp << 2);
                gc = (gc < 0) ? 0 : (gc > W_DIM - 4 ? W_DIM - 4 : gc);
                stg[it] = *(const float4*)(smn + c * HW + hic * W_DIM + gc);
            }
        }
    };
    // ---- stage-write (late): regs -> fp16 LDS buffer ----
    auto stage_write = [&](int bufi) {
        #pragma unroll
        for (int it = 0; it < NIT; ++it) {
            const int j = t + (it << 8);
            if (j < NJOB) {
                const int grp = j % NGX;
                const int rem = j / NGX;
                const int row = rem & 7;
                const int c   = rem >> 3;
                h4v p;
                p.lo = __floats2half2_rn(stg[it].x, stg[it].y);
                p.hi = __floats2half2_rn(stg[it].z, stg[it].w);
                *(h4v*)&sm_s[bufi][c][row][grp << 2] = p;
            }
        }
    };
    // ---- weights for tile at h0w -> w_h[bufi] (xyz from global, L2-hot) ----
    auto weights = [&](int h0w, int bufi) {
        const int whh = t >> 6;                // wave-uniform h-row
        const int wpl = t & 63;
        const int px  = w0 + wpl;
        const int h   = h0w + whh;
        const int ctr = h * W_DIM + px;
        const float cx = xyzn[ctr];
        const float cy = xyzn[HW + ctr];
        const float cz = xyzn[2 * HW + ctr];
        const bool edgeblk = (pc == 0) || (pc == 31);  // block-uniform

        #pragma unroll
        for (int r = 0; r < 5; ++r) {
            const int hi = h + r - 2;
            float w5[5];
            if ((unsigned)hi >= (unsigned)H_DIM) {
                #pragma unroll
                for (int dj = 0; dj < 5; ++dj) w5[dj] = 0.0f;
            } else {
                const int rb = hi * W_DIM;
                if (!edgeblk) {
                    const int o = rb + px - 2;
                    const float4 xv = *(const float4*)(xyzn + o);
                    const float  xs = xyzn[o + 4];
                    const float4 yv = *(const float4*)(xyzn + HW + o);
                    const float  ys = xyzn[HW + o + 4];
                    const float4 zv = *(const float4*)(xyzn + 2 * HW + o);
                    const float  zs = xyzn[2 * HW + o + 4];
                    const int4   mv = *(const int4*)(maskn + o);
                    const int    ms = maskn[o + 4];
                    const float nx[5] = {xv.x, xv.y, xv.z, xv.w, xs};
                    const float ny[5] = {yv.x, yv.y, yv.z, yv.w, ys};
                    const float nz[5] = {zv.x, zv.y, zv.z, zv.w, zs};
                    const int   nm[5] = {mv.x, mv.y, mv.z, mv.w, ms};
                    #pragma unroll
                    for (int dj = 0; dj < 5; ++dj) {
                        const float dx = nx[dj] - cx;
                        const float dy = ny[dj] - cy;
                        const float dz = nz[dj] - cz;
                        const float d2 = fmaf(dx, dx, fmaf(dy, dy, dz * dz));
                        w5[dj] = (nm[dj] != 0) ? __expf(-0.5f * d2) : 0.0f;
                    }
                } else {
                    #pragma unroll
                    for (int dj = 0; dj < 5; ++dj) {
                        const int col = px + dj - 2;
                        const bool cok = ((unsigned)col < (unsigned)W_DIM);
                        const int cc  = cok ? col : (col < 0 ? 0 : W_DIM - 1);
                        const int o   = rb + cc;
                        const float dx = xyzn[o] - cx;
                        const float dy = xyzn[HW + o] - cy;
                        const float dz = xyzn[2 * HW + o] - cz;
                        const float d2 = fmaf(dx, dx, fmaf(dy, dy, dz * dz));
                        const bool ok = cok && (maskn[o] != 0);
                        w5[dj] = ok ? __expf(-0.5f * d2) : 0.0f;
                    }
                }
            }
            #pragma unroll
            for (int dj = 0; dj < 5; ++dj)
                w_h[bufi][whh][r * 5 + dj][wpl] = __float2half_rn(w5[dj]);
        }
    };
    // ---- compute tile at h0c from buffers bufi (R13-verified phase 2) ----
    auto compute = [&](int bufi, int h0c) {
        const int cg = t >> 6;                 // channel group, wave-uniform
        const int hh = (t >> 4) & 3;           // h-row within tile
        const int pq = t & 15;                 // pixel quad
        const int cb = pq << 2;

        float4 acc[5];
        #pragma unroll
        for (int c = 0; c < 5; ++c) acc[c] = make_float4(0.f, 0.f, 0.f, 0.f);

        #pragma unroll
        for (int rt = 0; rt < 5; ++rt) {
            const int row = hh + rt;

            float4 wt[5];                      // 5 aligned b64, bank-uniform
            #pragma unroll
            for (int dj = 0; dj < 5; ++dj) {
                const h4v uw = *(const h4v*)&w_h[bufi][hh][rt * 5 + dj][cb];
                const float2 a  = __half22float2(uw.lo);
                const float2 bq = __half22float2(uw.hi);
                wt[dj] = make_float4(a.x, a.y, bq.x, bq.y);
            }

            #pragma unroll
            for (int c = 0; c < 5; ++c) {
                const __half* base = &sm_s[bufi][cg * 5 + c][row][0];
                const h4v u0 = *(const h4v*)(base + cb);      // cb..cb+3
                const h4v u1 = *(const h4v*)(base + cb + 4);  // cb+4..cb+7
                const h4v u2 = *(const h4v*)(base + cb + 8);  // cb+8..cb+11
                const float2 f01 = __half22float2(u0.hi);
                const float2 f23 = __half22float2(u1.lo);
                const float2 f45 = __half22float2(u1.hi);
                const float2 f67 = __half22float2(u2.lo);
                float fs[8];
                fs[0]=f01.x; fs[1]=f01.y; fs[2]=f23.x; fs[3]=f23.y;
                fs[4]=f45.x; fs[5]=f45.y; fs[6]=f67.x; fs[7]=f67.y;

                #pragma unroll
                for (int dj = 0; dj < 5; ++dj) {
                    acc[c].x = fmaf(wt[dj].x, fs[0 + dj], acc[c].x);
                    acc[c].y = fmaf(wt[dj].y, fs[1 + dj], acc[c].y);
                    acc[c].z = fmaf(wt[dj].z, fs[2 + dj], acc[c].z);
                    acc[c].w = fmaf(wt[dj].w, fs[3 + dj], acc[c].w);
                }
            }
        }

        const int ob = (h0c + hh) * W_DIM + w0 + cb;
        #pragma unroll
        for (int c = 0; c < 5; ++c)
            *(float4*)(outn + (cg * 5 + c) * HW + ob) = acc[c];
    };

    // ---------------- prologue: fill pipeline for tile 0 ----------------
    stage_issue(h0base);
    weights(h0base, 0);
    stage_write(0);
    __syncthreads();

    // ---------------- main loop: 8 tiles, 1 barrier each ----------------
    for (int tt = 0; tt < NT; ++tt) {
        const int cur = tt & 1;
        const int nxt = cur ^ 1;
        const int h0  = h0base + (tt << 2);

        if (tt < NT - 1) {
            stage_issue(h0 + HT);          // loads in flight across compute
            weights(h0 + HT, nxt);         // xyz L2-hot; writes w_h[nxt]
        }
        compute(cur, h0);                  // reads sm_s[cur], w_h[cur]
        if (tt < NT - 1) {
            stage_write(nxt);              // vmcnt covered by compute
        }
        __syncthreads();                   // guards cur<->nxt swap
    }
}

extern "C" void kernel_launch(void* const* d_in, const int* in_sizes, int n_in,
                              void* d_out, int out_size, void* d_ws, size_t ws_size,
                              hipStream_t stream)
{
    const float* xyz  = (const float*)d_in[0];
    const float* sm   = (const float*)d_in[1];
    const int*   mask = (const int*)d_in[2];
    float*       out  = (float*)d_out;

    const int grid = 32 * 2 * N_DIM;       // 512 blocks, 1D ONLY

    lcx_kernel<<<grid, BLOCK, 0, stream>>>(xyz, sm, mask, out);
}

// Round 12
// 215.269 us; speedup vs baseline: 1.3252x; 1.3252x over previous
//
#include <hip/hip_runtime.h>

// out[n,c,h,w] = sum_{5x5 in-bounds taps} exp(-0.5*||xyz_nbr - xyz_ctr||^2)
//                * mask_nbr * softmax[n,c,nbr]
// OOB taps have weight forced to 0, so staged/loaded slots at clamped
// addresses may hold garbage; they are always multiplied by 0.0f.
//
// R16 = R15 with the off-by-two window fix. R15 failed absmax 3.59:
// staged index s holds global col (w0 - 4 + s), so global col
// (px + dj - 2) is at s = wpl + dj + 2 -- R15 read wpl + dj (window
// shifted 2 cols left). Single-line fix; structure unchanged:
//   thread = (whh = t>>6, wpl = t&63) for BOTH weight and compute phases.
//   - 25 weights stay in VGPRs (no w_h LDS round-trip: R13 paid 25
//     ds_write + 100 ds_read + ~150 cvts/thread for mapping mismatch).
//   - whh wave-uniform -> whole wave reads ONE sm_s row at consecutive
//     cols -> conflict-free (2 lanes/bank = free).
//   - sm_s fp32 (46KB, 3 blocks/CU): zero cvts, absmax ~0.0156.
//   - compute: 20 ch x 5 rows x (5 scalar LDS reads + 5 FMA), unroll 4
//     over channels = 4 independent LDS chains (~120cy LDS latency, not
//     the global-load hazard that killed R9/R11).
// Dead ends confirmed: min-waves bounds (R6/R7 spill), global-fed inner
// loops (R8/R9/R11 pin 113-150us), manual pipelining (R14: occ 9%,
// 175us). Plain __launch_bounds__, ONE barrier.
// 1D grid ONLY (2D gridDim.y broke harness graph replay in R3).

#define H_DIM 64
#define W_DIM 2048
#define C_DIM 20
#define N_DIM 8
#define HW (H_DIM * W_DIM)
#define BLOCK 256
#define HT 4               // output h-rows per block
#define PX 64              // output pixels per block
#define RS 8               // staged rows = HT + 4
#define CS 72              // staged cols = PX + 8
#define NGX 18             // float4 groups per staged row
#define NJOB (C_DIM * RS * NGX)   // 2880 stage jobs

__global__ __launch_bounds__(BLOCK) void lcx_kernel(
    const float* __restrict__ xyz,
    const float* __restrict__ sm,
    const int*  __restrict__ mask,
    float* __restrict__ out)
{
    __shared__ float sm_s[C_DIM][RS][CS];   // 46.08 KB, fp32

    const int b  = blockIdx.x;              // 4096: 32 pxc x 16 htile x 8 n
    const int pc = b & 31;
    const int ht = (b >> 5) & 15;
    const int n  = b >> 9;
    const int w0 = pc << 6;
    const int h0 = ht << 2;
    const int t  = threadIdx.x;

    const float* xyzn  = xyz  + n * 3 * HW;
    const int*   maskn = mask + n * HW;
    const float* smn   = sm   + n * C_DIM * HW;
    float*       outn  = out  + n * C_DIM * HW;

    // ---- Phase S: stage sm halo -> fp32 LDS (2880 f4 jobs, indep loads) ----
    #pragma unroll
    for (int it = 0; it < 12; ++it) {
        const int j = t + (it << 8);
        if (j < NJOB) {                     // last iter: wave 0 only (uniform)
            const int grp = j % NGX;
            const int rem = j / NGX;        // c*8 + row
            const int row = rem & 7;
            const int c   = rem >> 3;
            const int hi  = h0 - 2 + row;
            const int hic = (hi < 0) ? 0 : (hi > H_DIM - 1 ? H_DIM - 1 : hi);
            int gc = w0 - 4 + (grp << 2);   // clamped groups are fully OOB
            gc = (gc < 0) ? 0 : (gc > W_DIM - 4 ? W_DIM - 4 : gc);
            *(float4*)&sm_s[c][row][grp << 2] =
                *(const float4*)(smn + c * HW + hic * W_DIM + gc);
        }
    }

    // ---- Phase W: 25 weights in REGISTERS for pixel (h0+whh, w0+wpl) ----
    const int whh = t >> 6;                 // wave-uniform h-row
    const int wpl = t & 63;
    const int px  = w0 + wpl;
    const int h   = h0 + whh;
    float w[25];
    {
        const int ctr = h * W_DIM + px;
        const float cx = xyzn[ctr];
        const float cy = xyzn[HW + ctr];
        const float cz = xyzn[2 * HW + ctr];
        const bool edgeblk = (pc == 0) || (pc == 31);  // block-uniform

        #pragma unroll
        for (int r = 0; r < 5; ++r) {
            const int hi = h + r - 2;
            float w5[5];
            if ((unsigned)hi >= (unsigned)H_DIM) {
                #pragma unroll
                for (int dj = 0; dj < 5; ++dj) w5[dj] = 0.0f;
            } else {
                const int rb = hi * W_DIM;
                if (!edgeblk) {
                    const int o = rb + px - 2;
                    const float4 xv = *(const float4*)(xyzn + o);
                    const float  xs = xyzn[o + 4];
                    const float4 yv = *(const float4*)(xyzn + HW + o);
                    const float  ys = xyzn[HW + o + 4];
                    const float4 zv = *(const float4*)(xyzn + 2 * HW + o);
                    const float  zs = xyzn[2 * HW + o + 4];
                    const int4   mv = *(const int4*)(maskn + o);
                    const int    ms = maskn[o + 4];
                    const float nx[5] = {xv.x, xv.y, xv.z, xv.w, xs};
                    const float ny[5] = {yv.x, yv.y, yv.z, yv.w, ys};
                    const float nz[5] = {zv.x, zv.y, zv.z, zv.w, zs};
                    const int   nm[5] = {mv.x, mv.y, mv.z, mv.w, ms};
                    #pragma unroll
                    for (int dj = 0; dj < 5; ++dj) {
                        const float dx = nx[dj] - cx;
                        const float dy = ny[dj] - cy;
                        const float dz = nz[dj] - cz;
                        const float d2 = fmaf(dx, dx, fmaf(dy, dy, dz * dz));
                        w5[dj] = (nm[dj] != 0) ? __expf(-0.5f * d2) : 0.0f;
                    }
                } else {
                    #pragma unroll
                    for (int dj = 0; dj < 5; ++dj) {
                        const int col = px + dj - 2;
                        const bool cok = ((unsigned)col < (unsigned)W_DIM);
                        const int cc  = cok ? col : (col < 0 ? 0 : W_DIM - 1);
                        const int o   = rb + cc;
                        const float dx = xyzn[o] - cx;
                        const float dy = xyzn[HW + o] - cy;
                        const float dz = xyzn[2 * HW + o] - cz;
                        const float d2 = fmaf(dx, dx, fmaf(dy, dy, dz * dz));
                        const bool ok = cok && (maskn[o] != 0);
                        w5[dj] = ok ? __expf(-0.5f * d2) : 0.0f;
                    }
                }
            }
            #pragma unroll
            for (int dj = 0; dj < 5; ++dj) w[r * 5 + dj] = w5[dj];
        }
    }
    __syncthreads();

    // ---- Phase C: 20 channels, all operands LDS/registers ----
    // staged index s holds global col (w0 - 4 + s), so the window for
    // global cols [px-2 .. px+2] starts at s = wpl + 2 (max 69 < 72).
    // Wave-uniform row -> consecutive-lane reads, conflict-free.
    const int octr = h * W_DIM + px;

    #pragma unroll 4
    for (int c = 0; c < C_DIM; ++c) {
        float a0 = 0.0f, a1 = 0.0f;
        #pragma unroll
        for (int rt = 0; rt < 5; ++rt) {
            const float* pr = &sm_s[c][whh + rt][wpl + 2];
            const float s0 = pr[0];
            const float s1 = pr[1];
            const float s2 = pr[2];
            const float s3 = pr[3];
            const float s4 = pr[4];
            a0 = fmaf(w[rt * 5 + 0], s0, a0);
            a1 = fmaf(w[rt * 5 + 1], s1, a1);
            a0 = fmaf(w[rt * 5 + 2], s2, a0);
            a1 = fmaf(w[rt * 5 + 3], s3, a1);
            a0 = fmaf(w[rt * 5 + 4], s4, a0);
        }
        outn[c * HW + octr] = a0 + a1;
    }
}

extern "C" void kernel_launch(void* const* d_in, const int* in_sizes, int n_in,
                              void* d_out, int out_size, void* d_ws, size_t ws_size,
                              hipStream_t stream)
{
    const float* xyz  = (const float*)d_in[0];
    const float* sm   = (const float*)d_in[1];
    const int*   mask = (const int*)d_in[2];
    float*       out  = (float*)d_out;

    const int grid = 32 * 16 * N_DIM;       // 4096 blocks, 1D ONLY

    lcx_kernel<<<grid, BLOCK, 0, stream>>>(xyz, sm, mask, out);
}